// Round 4
// baseline (414.335 us; speedup 1.0000x reference)
//
#include <hip/hip_runtime.h>
#include <hip/hip_bf16.h>

// CMDNet binary detector: per-batch Gram (MFMA bf16 2-term split, RN rounding)
// + 64 fixed-point iterations with HH held entirely in registers.
// One wave (64 lanes) per batch element, lane l owns output element m = l.
// 4 batches per 256-thread block; no cross-wave communication (no barriers).
// Iteration matvec uses v_pk_fma_f32 (2 FMA/instr) via float2 ext-vectors.

typedef __attribute__((ext_vector_type(8))) short bf16x8;
typedef __attribute__((ext_vector_type(4))) float f32x4;
typedef __attribute__((ext_vector_type(2))) float f32x2;
typedef __attribute__((ext_vector_type(4))) int i32x4;

union FragCast { i32x4 i; bf16x8 h; };

#define NTc 64
#define NRc 128

__device__ __forceinline__ float tanh_fast(float x) {
  // tanh(x) = 1 - 2/(exp(2x)+1); exp via v_exp_f32 (exp2). Safe at +/-inf:
  // x->+inf: u=inf -> 1; x->-inf: u=0 -> -1. No NaN for finite x.
  float u = __builtin_amdgcn_exp2f(x * 2.88539008177792681f); // 2*log2(e)
  return 1.0f - 2.0f * __builtin_amdgcn_rcpf(u + 1.0f);
}

__device__ __forceinline__ f32x2 pkfma(f32x2 a, f32x2 b, f32x2 c) {
#if __has_builtin(__builtin_elementwise_fma)
  return __builtin_elementwise_fma(a, b, c);   // lowers to v_pk_fma_f32
#else
  return c + a * b;                            // contracts to v_pk_fma_f32
#endif
}

__global__ __launch_bounds__(256, 3)
void cmdnet_bin_kernel(const float* __restrict__ yt, const float* __restrict__ Ht,
                       const float* __restrict__ sig0, const float* __restrict__ alpha,
                       const float* __restrict__ taui, const float* __restrict__ delta,
                       float* __restrict__ out, int B, int n_iter) {
  __shared__ __align__(16) float s_xt[4][64];

  const int tid = threadIdx.x;
  const int w = tid >> 6;        // wave in block
  const int l = tid & 63;        // lane
  const int g = l >> 4;          // lane group 0..3
  const int c = l & 15;          // col within 16-tile
  const int b = blockIdx.x * 4 + w;
  if (b >= B) return;            // wave-uniform exit (B % 4 == 0 anyway)

  const float* __restrict__ Hb = Ht + (size_t)b * (NRc * NTc);
  const float* __restrict__ yb = yt + (size_t)b * NRc;

  const bool hi2 = (g & 2) != 0;
  const bool odd = (g & 1) != 0;

  // ---- Phase 1: HH = Ht^T Ht via MFMA 16x16x32 bf16, 2-term RN split ----
  // acc[i][q]: lane holds HH[16i + g*4 + r][16q + c]  (r = reg 0..3)
  // Robust to MFMA A/B k-permutation: both operands use identical physical
  // slots, and HH symmetry makes even an A<->B transpose convention benign.
  f32x4 acc[4][4];
  #pragma unroll
  for (int i = 0; i < 4; i++)
    #pragma unroll
    for (int j = 0; j < 4; j++) acc[i][j] = (f32x4)0.0f;

  float yhp[4] = {0.0f, 0.0f, 0.0f, 0.0f};  // yH partials per 16-col block

  const int base_l = (g * 8) * NTc + c;

  #pragma unroll
  for (int kk = 0; kk < 4; kk++) {       // K-chunks of 32 rows of Ht[b]
    const float4 ya  = *reinterpret_cast<const float4*>(yb + kk * 32 + g * 8);
    const float4 yb4 = *reinterpret_cast<const float4*>(yb + kk * 32 + g * 8 + 4);
    const float yv[8] = {ya.x, ya.y, ya.z, ya.w, yb4.x, yb4.y, yb4.z, yb4.w};

    FragCast fh[4], fl[4];
    #pragma unroll
    for (int p = 0; p < 4; p++) {        // 4 column-blocks of 16
      #pragma unroll
      for (int jj = 0; jj < 4; jj++) {   // packed word jj holds rows 2jj, 2jj+1
        float v0 = Hb[base_l + kk * 32 * NTc + (2 * jj) * NTc + p * 16];
        float v1 = Hb[base_l + kk * 32 * NTc + (2 * jj + 1) * NTc + p * 16];
        yhp[p] = fmaf(yv[2 * jj], v0, yhp[p]);
        yhp[p] = fmaf(yv[2 * jj + 1], v1, yhp[p]);
        // Round-to-nearest bf16 hi extraction: residual |r| <= 2^-9 |v|
        // (vs 2^-8 for truncation). r = v - hi is exact in f32.
        unsigned b0 = __float_as_uint(v0), b1 = __float_as_uint(v1);
        unsigned h0 = (b0 + 0x8000u) & 0xffff0000u;
        unsigned h1 = (b1 + 0x8000u) & 0xffff0000u;
        float r0 = v0 - __uint_as_float(h0);
        float r1 = v1 - __uint_as_float(h1);
        fh[p].i[jj] = (int)((h0 >> 16) | h1);
        // RN-pack lo as well.
        fl[p].i[jj] = (int)(((__float_as_uint(r0) + 0x8000u) >> 16) |
                            ((__float_as_uint(r1) + 0x8000u) & 0xffff0000u));
      }
    }
    // D += hi*hi + hi*lo + lo*hi  (dropped lo*lo ~2^-18 relative)
    #pragma unroll
    for (int p = 0; p < 4; p++) {
      #pragma unroll
      for (int q = 0; q < 4; q++) {
        acc[p][q] = __builtin_amdgcn_mfma_f32_16x16x32_bf16(fh[p].h, fh[q].h, acc[p][q], 0, 0, 0);
        acc[p][q] = __builtin_amdgcn_mfma_f32_16x16x32_bf16(fh[p].h, fl[q].h, acc[p][q], 0, 0, 0);
        acc[p][q] = __builtin_amdgcn_mfma_f32_16x16x32_bf16(fl[p].h, fh[q].h, acc[p][q], 0, 0, 0);
      }
    }
  }

  // yH reduce-scatter: lane needs yH[l] = yH[16g + c]; partials are over
  // 32 rows per lane (its g). Round 1 over lane^32, round 2 over lane^16.
  float yH_l;
  {
    float sA = hi2 ? yhp[2] : yhp[0];
    float sB = hi2 ? yhp[3] : yhp[1];
    float oA = hi2 ? yhp[0] : yhp[2];
    float oB = hi2 ? yhp[1] : yhp[3];
    sA += __shfl_xor(oA, 32);
    sB += __shfl_xor(oB, 32);
    float keep = odd ? sB : sA;
    float send = odd ? sA : sB;
    yH_l = keep + __shfl_xor(send, 16);
  }

  // ---- Per-lane constants ----
  const float a_l = alpha[l];
  const float c_l = logf(1.0f / a_l - 1.0f);
  const float sg = sig0[b];
  const float sig2 = sg * sg;

  // ---- Phase 2: n_iter fixed-point iterations ----
  float s = 0.0f;
  float taa = 1.0f;

  for (int it = 0; it < n_iter; it++) {
    const float de = delta[it];
    taa = fabsf(taui[it]);
    const float tx = (it == 0) ? 1.0f : taa;   // first layer: temperature 1
    const float xtv = tanh_fast((c_l + s) * 0.5f * tx);

    s_xt[w][l] = xtv;  // DS ops are in-order per wave; no barrier needed

    // Matvec xHH = xt . HH via packed FMAs (v_pk_fma_f32): accumulate the
    // register-adjacent (r0,r1)/(r2,r3) halves of each acc[i][q] in f32x2.
    f32x2 q0 = {0.0f, 0.0f}, q1 = {0.0f, 0.0f};
    f32x2 q2 = {0.0f, 0.0f}, q3 = {0.0f, 0.0f};
    #pragma unroll
    for (int i = 0; i < 4; i++) {
      const f32x4 xv = *reinterpret_cast<const f32x4*>(&s_xt[w][i * 16 + g * 4]);
      const f32x2 xlo = xv.xy, xhi = xv.zw;
      q0 = pkfma(xlo, acc[i][0].xy, q0); q0 = pkfma(xhi, acc[i][0].zw, q0);
      q1 = pkfma(xlo, acc[i][1].xy, q1); q1 = pkfma(xhi, acc[i][1].zw, q1);
      q2 = pkfma(xlo, acc[i][2].xy, q2); q2 = pkfma(xhi, acc[i][2].zw, q2);
      q3 = pkfma(xlo, acc[i][3].xy, q3); q3 = pkfma(xhi, acc[i][3].zw, q3);
    }
    float p0 = q0.x + q0.y, p1 = q1.x + q1.y;
    float p2 = q2.x + q2.y, p3 = q3.x + q3.y;

    // Reduce-scatter: lane group g keeps only P[g] (= xHH[l]). 3 shfls.
    float sA = hi2 ? p2 : p0;
    float sB = hi2 ? p3 : p1;
    float oA = hi2 ? p0 : p2;
    float oB = hi2 ? p1 : p3;
    sA += __shfl_xor(oA, 32);
    sB += __shfl_xor(oB, 32);
    float keep = odd ? sB : sA;
    float send = odd ? sA : sB;
    const float xHH = keep + __shfl_xor(send, 16);

    const float grad = sig2 * tanh_fast(s * 0.5f) +
                       0.5f * taa * (1.0f - xtv * xtv) * (xHH - yH_l);
    s = s - de * grad;
  }

  // ---- Epilogue: ft = [(1-xt)/2, (1+xt)/2], then xt (uses last taui) ----
  const float xtf = tanh_fast((c_l + s) * 0.5f * taa);
  float2 ft;
  ft.x = 0.5f * (1.0f - xtf);
  ft.y = 0.5f * (1.0f + xtf);
  *reinterpret_cast<float2*>(out + ((size_t)b * NTc + l) * 2) = ft;
  out[(size_t)B * NTc * 2 + (size_t)b * NTc + l] = xtf;
}

extern "C" void kernel_launch(void* const* d_in, const int* in_sizes, int n_in,
                              void* d_out, int out_size, void* d_ws, size_t ws_size,
                              hipStream_t stream) {
  const float* yt    = (const float*)d_in[0];
  const float* Ht    = (const float*)d_in[1];
  const float* sig0  = (const float*)d_in[2];
  const float* alpha = (const float*)d_in[3];
  const float* taui  = (const float*)d_in[4];
  const float* delta = (const float*)d_in[5];
  const int B = in_sizes[2];        // sigmat0 is [B]
  const int n_iter = in_sizes[4];   // taui is [NUM_ITER]

  const int blocks = (B + 3) / 4;   // 4 batches (one wave each) per block
  hipLaunchKernelGGL(cmdnet_bin_kernel, dim3(blocks), dim3(256), 0, stream,
                     yt, Ht, sig0, alpha, taui, delta, (float*)d_out, B, n_iter);
}